// Round 1
// baseline (109.668 us; speedup 1.0000x reference)
//
#include <hip/hip_runtime.h>

#define IGNORE_LABEL (-100)

// Layout of d_out (flat float32):
//   [0, P*128)            projected features
//   [P*128, P*128 + P)    indexes_image passthrough (as float)
//   [P*128 + P, ... + V)  mapping3dto2d_num (as float, via atomicAdd of 1.0f)
//
// 32 lanes cooperate on one pixel: each lane moves one float4 (512 B/row total).
__global__ void RaycastFeatures_42597485641917_kernel(
        const float4* __restrict__ feat,   // [V][32] float4 view of [V][128] f32
        const int*    __restrict__ idx,    // [P]
        float4*       __restrict__ proj,   // [P][32] float4 view
        float*        __restrict__ idx_out,// [P]
        float*        __restrict__ counts, // [V], pre-zeroed
        int P) {
    const int tid  = blockIdx.x * blockDim.x + threadIdx.x;
    const int lane = tid & 31;                       // position within 32-lane group
    const int grp0 = tid >> 5;
    const int ngrp = (gridDim.x * blockDim.x) >> 5;  // groups in flight

    for (int p = grp0; p < P; p += ngrp) {
        const int  v     = idx[p];          // same addr across 32 lanes -> broadcast
        const bool valid = (v != IGNORE_LABEL);

        if (lane == 0) {
            idx_out[p] = (float)v;
            if (valid) atomicAdd(&counts[v], 1.0f);
        }

        float4 val = make_float4(0.f, 0.f, 0.f, 0.f);
        if (valid) val = feat[(size_t)v * 32 + lane];
        proj[(size_t)p * 32 + lane] = val;
    }
}

extern "C" void kernel_launch(void* const* d_in, const int* in_sizes, int n_in,
                              void* d_out, int out_size, void* d_ws, size_t ws_size,
                              hipStream_t stream) {
    const float* feat = (const float*)d_in[0];   // [V,128] f32
    const int*   idx  = (const int*)d_in[1];     // [B,NV,H,W] i32 flattened

    const int D = 128;                 // feature dim (fixed by reference setup)
    const int V = in_sizes[0] / D;     // 100000
    const int P = in_sizes[1];         // 614400

    float* out     = (float*)d_out;
    float4* proj   = (float4*)out;
    float* idx_out = out + (size_t)P * D;
    float* counts  = idx_out + P;

    // Zero the count bins each call (harness poisons once, never re-poisons;
    // atomics must start from 0 every replay). Memset node is capture-legal.
    hipMemsetAsync(counts, 0, (size_t)V * sizeof(float), stream);

    const int block = 256;             // 8 pixel-groups per block
    const int grid  = 2048;            // 8 blocks/CU -> full occupancy, grid-stride
    RaycastFeatures_42597485641917_kernel<<<grid, block, 0, stream>>>(
        (const float4*)feat, idx, proj, idx_out, counts, P);
}